// Round 8
// baseline (267.233 us; speedup 1.0000x reference)
//
#include <hip/hip_runtime.h>
#include <math.h>

#define BB 2
#define SS 2048
#define EE 1024
#define HH 16
#define LL 5
#define DH 64
#define QS (3 * 1024)  // QKV fused row stride

typedef __attribute__((ext_vector_type(8))) short bf16x8;
typedef __attribute__((ext_vector_type(4))) float f32x4;

__device__ __forceinline__ unsigned short f2bf(float f) {
  unsigned u = __float_as_uint(f);
  u += 0x7fffu + ((u >> 16) & 1u);
  return (unsigned short)(u >> 16);
}
__device__ __forceinline__ float bf2f(unsigned short u) {
  return __uint_as_float((unsigned)u << 16);
}
__device__ __forceinline__ f32x4 mfma16(bf16x8 a, bf16x8 b, f32x4 c) {
  return __builtin_amdgcn_mfma_f32_16x16x32_bf16(a, b, c, 0, 0, 0);
}
// packed f32x2 -> bf16x2 (RNE), no builtin on gfx950 -> inline asm
__device__ __forceinline__ unsigned cvtpk(float a, float b) {
  unsigned r;
  asm("v_cvt_pk_bf16_f32 %0, %1, %2" : "=v"(r) : "v"(a), "v"(b));
  return r;
}
// async global->LDS, 16B per lane. lds dest must be wave-uniform base + lane*16.
__device__ __forceinline__ void gload16(const unsigned short* g, unsigned short* l) {
  __builtin_amdgcn_global_load_lds(
      (const __attribute__((address_space(1))) void*)g,
      (__attribute__((address_space(3))) void*)l, 16, 0, 0);
}

// ---------------------------------------------------------------------------
// prep_pack: factor[b][h] (thread 0); beff[b][e]; bqkv = [bq|bk|bv].
// cl computed inline from cons (cl[b][l] = cons[b*HH + l], since l%HH = l).
// grid 20 x 256 covers BB*EE + QS = 5120.
// ---------------------------------------------------------------------------
__global__ void prep_pack(const float* __restrict__ cons, const float* __restrict__ gate,
                          const float* __restrict__ bc,
                          const float* __restrict__ bq, const float* __restrict__ bk,
                          const float* __restrict__ bv,
                          float* __restrict__ beff, float* __restrict__ bqkv,
                          float* __restrict__ factor) {
  int i = blockIdx.x * 256 + threadIdx.x;
  if (i == 0) {
    float gw[LL][HH];
    for (int l = 0; l < LL; ++l) {
      float mx = -1e30f;
      for (int h = 0; h < HH; ++h) mx = fmaxf(mx, gate[l * HH + h]);
      float s = 0.f;
      for (int h = 0; h < HH; ++h) { gw[l][h] = expf(gate[l * HH + h] - mx); s += gw[l][h]; }
      for (int h = 0; h < HH; ++h) gw[l][h] /= s;
    }
    for (int b = 0; b < BB; ++b)
      for (int h = 0; h < HH; ++h) {
        float f = 1.f;
        for (int l = 0; l < LL; ++l) f *= 1.f + 0.1f * cons[b * HH + l] * gw[l][h];
        factor[b * HH + h] = f;
      }
  }
  if (i < BB * EE) {
    int b = i >> 10, e = i & 1023;
    float a = 0.f;
    #pragma unroll
    for (int l = 0; l < LL; ++l) a += cons[b * HH + l] * bc[l * EE + e];
    beff[i] = a * (1.f / LL);
  } else {
    int j = i - BB * EE;  // 0..3071
    float v = (j < EE) ? bq[j] : (j < 2 * EE) ? bk[j - EE] : bv[j - 2 * EE];
    bqkv[j] = v;
  }
}

// ---------------------------------------------------------------------------
// Wefft[b][o][e] (bf16) = transpose of (1/L) sum_l cl[b,l]*Wc[l][e][o].
// ---------------------------------------------------------------------------
__global__ __launch_bounds__(256) void wceffT_kernel(const float* __restrict__ Wc,
                                                     const float* __restrict__ cons,
                                                     unsigned short* __restrict__ Wt) {
  int o0 = blockIdx.x * 64, e0 = blockIdx.y * 64, b = blockIdx.z;
  __shared__ float t[64][69];
  int tid = threadIdx.x;
  float w[LL];
  #pragma unroll
  for (int l = 0; l < LL; ++l) w[l] = cons[b * HH + l] * (1.f / LL);
  #pragma unroll
  for (int i = 0; i < 4; ++i) {
    int idx = tid + i * 256;
    int r = idx >> 4, c4 = idx & 15;
    float4 acc = {0.f, 0.f, 0.f, 0.f};
    #pragma unroll
    for (int l = 0; l < LL; ++l) {
      float4 v = *(const float4*)&Wc[(long)l * EE * EE + (long)(e0 + r) * EE + o0 + c4 * 4];
      acc.x += w[l] * v.x; acc.y += w[l] * v.y; acc.z += w[l] * v.z; acc.w += w[l] * v.w;
    }
    t[r][c4 * 4 + 0] = acc.x; t[r][c4 * 4 + 1] = acc.y;
    t[r][c4 * 4 + 2] = acc.z; t[r][c4 * 4 + 3] = acc.w;
  }
  __syncthreads();
  #pragma unroll
  for (int i = 0; i < 2; ++i) {
    int idx = tid + i * 256;
    int o = idx >> 3, ech = idx & 7;
    unsigned short u[8];
    #pragma unroll
    for (int j = 0; j < 8; ++j) u[j] = f2bf(t[ech * 8 + j][o]);
    unsigned short* dst = Wt + (long)b * EE * EE + (long)(o0 + o) * EE + e0 + ech * 8;
    *(ushort4*)&dst[0] = *(ushort4*)&u[0];
    *(ushort4*)&dst[4] = *(ushort4*)&u[4];
  }
}

// ---------------------------------------------------------------------------
// wT4: transpose-convert Wq/Wk/Wv/Wo (f32 [k][n] -> bf16 [n][k]) in one launch.
// ---------------------------------------------------------------------------
__global__ __launch_bounds__(256) void wT4_kernel(
    const float* __restrict__ W0, const float* __restrict__ W1,
    const float* __restrict__ W2, const float* __restrict__ W3,
    unsigned short* __restrict__ Wqkvt, unsigned short* __restrict__ Wot) {
  int z = blockIdx.z;
  const float* W = (z == 0) ? W0 : (z == 1) ? W1 : (z == 2) ? W2 : W3;
  unsigned short* Wt = (z < 3) ? (Wqkvt + (size_t)z * EE * EE) : Wot;
  int o0 = blockIdx.x * 64, e0 = blockIdx.y * 64;
  __shared__ float t[64][69];
  int tid = threadIdx.x;
  #pragma unroll
  for (int i = 0; i < 4; ++i) {
    int idx = tid + i * 256;
    int r = idx >> 4, c4 = idx & 15;
    float4 v = *(const float4*)&W[(long)(e0 + r) * EE + o0 + c4 * 4];
    t[r][c4 * 4 + 0] = v.x; t[r][c4 * 4 + 1] = v.y;
    t[r][c4 * 4 + 2] = v.z; t[r][c4 * 4 + 3] = v.w;
  }
  __syncthreads();
  #pragma unroll
  for (int i = 0; i < 2; ++i) {
    int idx = tid + i * 256;
    int o = idx >> 3, ech = idx & 7;
    unsigned short u[8];
    #pragma unroll
    for (int j = 0; j < 8; ++j) u[j] = f2bf(t[ech * 8 + j][o]);
    unsigned short* dst = Wt + (long)(o0 + o) * EE + e0 + ech * 8;
    *(ushort4*)&dst[0] = *(ushort4*)&u[0];
    *(ushort4*)&dst[4] = *(ushort4*)&u[4];
  }
}

// f32 -> bf16 convert, 8 elems/thread.
__global__ void cvt_bf_kernel(const float* __restrict__ in, unsigned short* __restrict__ out) {
  long i = (long)blockIdx.x * 256 + threadIdx.x;
  float4 a = ((const float4*)in)[i * 2];
  float4 b = ((const float4*)in)[i * 2 + 1];
  ushort4 u0 = make_ushort4(f2bf(a.x), f2bf(a.y), f2bf(a.z), f2bf(a.w));
  ushort4 u1 = make_ushort4(f2bf(b.x), f2bf(b.y), f2bf(b.z), f2bf(b.w));
  ((ushort4*)out)[i * 2] = u0;
  ((ushort4*)out)[i * 2 + 1] = u1;
}

// ---------------------------------------------------------------------------
// bf16 MFMA GEMM, 128x64 tile. Used for ce / out-proj.
// ---------------------------------------------------------------------------
template <int OUTBF>
__global__ __launch_bounds__(256) void gemm_bf(
    const unsigned short* __restrict__ A, const unsigned short* __restrict__ Bt,
    const float* __restrict__ bias, void* __restrict__ C,
    int N, int K, long As_z, long Ws_z, long Bs_z, long Cs_z) {
  int flat = blockIdx.x + gridDim.x * (blockIdx.y + gridDim.y * blockIdx.z);
  int nwg = gridDim.x * gridDim.y * gridDim.z;
  flat = (flat & 7) * (nwg >> 3) + (flat >> 3);
  int nt_ = flat % gridDim.x;
  int rest = flat / gridDim.x;
  int mt_ = rest % gridDim.y;
  int z = rest / gridDim.y;

  const unsigned short* Ab = A + z * As_z + (long)mt_ * 128 * K;
  const unsigned short* Bb = Bt + z * Ws_z + (long)nt_ * 64 * K;
  const float* bb = bias + z * Bs_z + nt_ * 64;

  __shared__ __align__(16) unsigned short As[2][128 * 64];
  __shared__ __align__(16) unsigned short Bs[2][64 * 64];
  int tid = threadIdx.x;
  int w = tid >> 6, lane = tid & 63, c = lane & 15, g = lane >> 4;
  int wrow = (w >> 1) * 64, wcol = (w & 1) * 32;

  #define STAGE_A(kt, buf)                                                     \
    {                                                                          \
      const unsigned short* s_ = Ab + (kt) * 64;                               \
      _Pragma("unroll") for (int j = 0; j < 4; ++j) {                          \
        int base = (w * 4 + j) * 64;                                           \
        int idx = base + lane;                                                 \
        int row = idx >> 3, ch = idx & 7;                                      \
        gload16(s_ + (long)row * K + ((ch ^ (row & 7)) << 3),                  \
                &As[buf][base * 8]);                                           \
      }                                                                        \
    }
  #define STAGE_B(kt, buf)                                                     \
    {                                                                          \
      const unsigned short* s_ = Bb + (kt) * 64;                               \
      _Pragma("unroll") for (int j = 0; j < 2; ++j) {                          \
        int base = (w * 2 + j) * 64;                                           \
        int idx = base + lane;                                                 \
        int row = idx >> 3, ch = idx & 7;                                      \
        gload16(s_ + (long)row * K + ((ch ^ (row & 7)) << 3),                  \
                &Bs[buf][base * 8]);                                           \
      }                                                                        \
    }

  f32x4 acc[4][2];
  #pragma unroll
  for (int mi = 0; mi < 4; ++mi)
    #pragma unroll
    for (int ni = 0; ni < 2; ++ni) acc[mi][ni] = {0.f, 0.f, 0.f, 0.f};

  int nk = K >> 6;
  STAGE_A(0, 0) STAGE_B(0, 0)
  __syncthreads();
  int buf = 0;
  for (int kt = 0; kt < nk; ++kt) {
    if (kt + 1 < nk) { STAGE_A(kt + 1, buf ^ 1) STAGE_B(kt + 1, buf ^ 1) }
    #pragma unroll
    for (int kk = 0; kk < 2; ++kk) {
      bf16x8 af[4], bfv[2];
      #pragma unroll
      for (int mi = 0; mi < 4; ++mi) {
        int row = wrow + mi * 16 + c;
        af[mi] = *(const bf16x8*)&As[buf][row * 64 + ((((kk << 2) + g) ^ (row & 7)) << 3)];
      }
      #pragma unroll
      for (int ni = 0; ni < 2; ++ni) {
        int row = wcol + ni * 16 + c;
        bfv[ni] = *(const bf16x8*)&Bs[buf][row * 64 + ((((kk << 2) + g) ^ (row & 7)) << 3)];
      }
      #pragma unroll
      for (int mi = 0; mi < 4; ++mi)
        #pragma unroll
        for (int ni = 0; ni < 2; ++ni)
          acc[mi][ni] = mfma16(af[mi], bfv[ni], acc[mi][ni]);
    }
    __syncthreads();
    buf ^= 1;
  }

  float bval[2] = {bb[wcol + c], bb[wcol + 16 + c]};
  #pragma unroll
  for (int mi = 0; mi < 4; ++mi)
    #pragma unroll
    for (int ni = 0; ni < 2; ++ni) {
      long col = (long)nt_ * 64 + wcol + ni * 16 + c;
      #pragma unroll
      for (int r = 0; r < 4; ++r) {
        long row = (long)mt_ * 128 + wrow + mi * 16 + g * 4 + r;
        float v = acc[mi][ni][r] + bval[ni];
        if (OUTBF)
          ((unsigned short*)C)[z * Cs_z + row * N + col] = f2bf(v);
        else
          ((float*)C)[z * Cs_z + row * N + col] = v;
      }
    }
  #undef STAGE_A
  #undef STAGE_B
}

// ---------------------------------------------------------------------------
// bf16 MFMA GEMM, 128x128 tile (m97 structure). Used for QKV (N=3072).
// ---------------------------------------------------------------------------
__global__ __launch_bounds__(256) void gemm128(
    const unsigned short* __restrict__ A, const unsigned short* __restrict__ Bt,
    const float* __restrict__ bias, unsigned short* __restrict__ C,
    int N, int K, long As_z, long Cs_z) {
  int flat = blockIdx.x + gridDim.x * (blockIdx.y + gridDim.y * blockIdx.z);
  int nwg = gridDim.x * gridDim.y * gridDim.z;
  flat = (flat & 7) * (nwg >> 3) + (flat >> 3);
  int nt_ = flat % gridDim.x;
  int rest = flat / gridDim.x;
  int mt_ = rest % gridDim.y;
  int z = rest / gridDim.y;

  const unsigned short* Ab = A + z * As_z + (long)mt_ * 128 * K;
  const unsigned short* Bb = Bt + (long)nt_ * 128 * K;
  const float* bb = bias + nt_ * 128;

  __shared__ __align__(16) unsigned short As[2][128 * 64];
  __shared__ __align__(16) unsigned short Bs[2][128 * 64];
  int tid = threadIdx.x;
  int w = tid >> 6, lane = tid & 63, c = lane & 15, g = lane >> 4;
  int wrow = (w >> 1) * 64, wcol = (w & 1) * 64;

  #define STG128(srcp, dstbuf, kt)                                             \
    {                                                                          \
      const unsigned short* s_ = (srcp) + (kt) * 64;                           \
      _Pragma("unroll") for (int j = 0; j < 4; ++j) {                          \
        int idx = tid + j * 256;                                               \
        int row = idx >> 3, ch = idx & 7;                                      \
        gload16(s_ + (long)row * K + ((ch ^ (row & 7)) << 3),                  \
                &dstbuf[(idx & ~63) * 8 + (lane)*8]);                          \
      }                                                                        \
    }

  f32x4 acc[4][4];
  #pragma unroll
  for (int mi = 0; mi < 4; ++mi)
    #pragma unroll
    for (int ni = 0; ni < 4; ++ni) acc[mi][ni] = {0.f, 0.f, 0.f, 0.f};

  int nk = K >> 6;
  STG128(Ab, As[0], 0) STG128(Bb, Bs[0], 0)
  __syncthreads();
  int buf = 0;
  for (int kt = 0; kt < nk; ++kt) {
    if (kt + 1 < nk) { STG128(Ab, As[buf ^ 1], kt + 1) STG128(Bb, Bs[buf ^ 1], kt + 1) }
    #pragma unroll
    for (int kk = 0; kk < 2; ++kk) {
      bf16x8 af[4], bfv[4];
      #pragma unroll
      for (int mi = 0; mi < 4; ++mi) {
        int row = wrow + mi * 16 + c;
        af[mi] = *(const bf16x8*)&As[buf][row * 64 + ((((kk << 2) + g) ^ (row & 7)) << 3)];
      }
      #pragma unroll
      for (int ni = 0; ni < 4; ++ni) {
        int row = wcol + ni * 16 + c;
        bfv[ni] = *(const bf16x8*)&Bs[buf][row * 64 + ((((kk << 2) + g) ^ (row & 7)) << 3)];
      }
      #pragma unroll
      for (int mi = 0; mi < 4; ++mi)
        #pragma unroll
        for (int ni = 0; ni < 4; ++ni)
          acc[mi][ni] = mfma16(af[mi], bfv[ni], acc[mi][ni]);
    }
    __syncthreads();
    buf ^= 1;
  }

  float bval[4];
  #pragma unroll
  for (int ni = 0; ni < 4; ++ni) bval[ni] = bb[wcol + ni * 16 + c];
  #pragma unroll
  for (int mi = 0; mi < 4; ++mi)
    #pragma unroll
    for (int ni = 0; ni < 4; ++ni) {
      long col = (long)nt_ * 128 + wcol + ni * 16 + c;
      #pragma unroll
      for (int r = 0; r < 4; ++r) {
        long row = (long)mt_ * 128 + wrow + mi * 16 + g * 4 + r;
        C[z * Cs_z + row * N + col] = f2bf(acc[mi][ni][r] + bval[ni]);
      }
    }
  #undef STG128
}

// ---------------------------------------------------------------------------
// mean2: partial mean over s of Q (z=0) and K (z=1) slices of QKV.
// ---------------------------------------------------------------------------
__global__ void mean2_kernel(const unsigned short* __restrict__ QKVb,
                             float* __restrict__ Qm, float* __restrict__ Km) {
  int z = blockIdx.z;
  const unsigned short* in = QKVb + z * EE;
  float* out = z ? Km : Qm;
  int e = blockIdx.x * 256 + threadIdx.x;
  int b = e >> 10, ee = e & 1023;
  int s0 = blockIdx.y * 128;
  const unsigned short* p = in + ((long)b * SS + s0) * QS + ee;
  float acc = 0.f;
  for (int i = 0; i < 128; ++i) acc += bf2f(p[(long)i * QS]);
  atomicAdd(&out[e], acc * (1.f / SS));
}

// ---------------------------------------------------------------------------
// alpha[b,h] = 1 + sigmoid( gelu(ci @ Wc1 + bc1) @ Wc2 + bc2 ).
// ---------------------------------------------------------------------------
__global__ __launch_bounds__(256) void cw_kernel(
    const float* __restrict__ Qm, const float* __restrict__ Km,
    const float* __restrict__ Wc1, const float* __restrict__ bc1,
    const float* __restrict__ Wc2, const float* __restrict__ bc2,
    float* __restrict__ alpha) {
  int bh = blockIdx.x, b = bh / HH, h = bh % HH;
  __shared__ float ci[128];
  __shared__ float pr[4];
  int tid = threadIdx.x;
  if (tid < 64) ci[tid] = Qm[b * EE + h * DH + tid];
  else if (tid < 128) ci[tid] = Km[b * EE + h * DH + (tid - 64)];
  __syncthreads();
  float part = 0.f;
  for (int j = tid; j < EE; j += 256) {
    float acc = bc1[j];
    #pragma unroll 8
    for (int i = 0; i < 128; ++i) acc += ci[i] * Wc1[i * EE + j];
    float ge = 0.5f * acc * (1.f + erff(acc * 0.70710678118654752f));
    part += ge * Wc2[j];
  }
  #pragma unroll
  for (int off = 32; off; off >>= 1) part += __shfl_xor(part, off);
  if ((tid & 63) == 0) pr[tid >> 6] = part;
  __syncthreads();
  if (tid == 0) {
    float tot = pr[0] + pr[1] + pr[2] + pr[3] + bc2[0];
    float cw = 1.f / (1.f + expf(-tot));
    alpha[bh] = 1.f + cw;
  }
}

// ---------------------------------------------------------------------------
// Repack V bf16 (QKV fused, stride QS) -> bf16 transposed Vt[bh][d][s].
// ---------------------------------------------------------------------------
__global__ __launch_bounds__(256) void repack_vT(const unsigned short* __restrict__ Vh,
                                                 unsigned short* __restrict__ Vt) {
  int st = blockIdx.x, h = blockIdx.y, b = blockIdx.z;
  __shared__ unsigned short tile[64][66];
  int tid = threadIdx.x;
  const unsigned short* src = Vh + ((long)(b * SS) + st * 64) * QS + h * 64;
  #pragma unroll
  for (int i = 0; i < 2; ++i) {
    int idx = tid + i * 256;
    int s = idx >> 3, ch = idx & 7;
    #pragma unroll
    for (int j = 0; j < 8; ++j) tile[s][ch * 8 + j] = src[(long)s * QS + ch * 8 + j];
  }
  __syncthreads();
  unsigned short* dst = Vt + ((long)(b * HH + h) * 64) * SS + st * 64;
  #pragma unroll
  for (int i = 0; i < 2; ++i) {
    int idx = tid + i * 256;
    int d = idx >> 3, sch = idx & 7;
    unsigned short u[8];
    #pragma unroll
    for (int j = 0; j < 8; ++j) u[j] = tile[sch * 8 + j][d];
    *(ushort4*)&dst[(long)d * SS + sch * 8] = *(ushort4*)&u[0];
    *(ushort4*)&dst[(long)d * SS + sch * 8 + 4] = *(ushort4*)&u[4];
  }
}

// ---------------------------------------------------------------------------
// Vsum[bh*64+d] = sum_s Vt[bh][d][s].  One wave per row.
// ---------------------------------------------------------------------------
__global__ __launch_bounds__(256) void vsum_kernel(const unsigned short* __restrict__ Vt,
                                                   float* __restrict__ Vsum) {
  int row = blockIdx.x * 4 + (threadIdx.x >> 6);
  int lane = threadIdx.x & 63;
  const unsigned short* p = Vt + (long)row * SS + lane * 32;
  float acc = 0.f;
  #pragma unroll
  for (int i = 0; i < 4; ++i) {
    uint4 v = *(const uint4*)(p + i * 8);
    unsigned arr[4] = {v.x, v.y, v.z, v.w};
    #pragma unroll
    for (int j = 0; j < 4; ++j) {
      acc += __uint_as_float(arr[j] << 16);
      acc += __uint_as_float(arr[j] & 0xffff0000u);
    }
  }
  #pragma unroll
  for (int off = 32; off; off >>= 1) acc += __shfl_xor(acc, off);
  if (lane == 0) Vsum[row] = acc;
}

// ---------------------------------------------------------------------------
// Linearized attention v3: 4 waves x 64 q = 256 q/block; t-split x4 (512 t).
// K/V LDS reads amortize over 2x MFMA vs round 7 (8 K + 8 V reads -> 64 MFMA).
// LDS 32KB: K 8 + V 8 + P 4x4KB. Single-buffered K/V, T14 reg-staging.
// Partials: m1p[part][b][h][s] f32; Np[part][b][s][e] bf16.
// ---------------------------------------------------------------------------
__global__ __launch_bounds__(256, 3) void attn_lin(
    const unsigned short* __restrict__ QKV,  // [b][s][3072]
    const unsigned short* __restrict__ Vt,   // [bh][d][s]
    const float* __restrict__ alpha,
    unsigned short* __restrict__ Np0, unsigned short* __restrict__ Np1,
    unsigned short* __restrict__ Np2, unsigned short* __restrict__ Np3,
    float* __restrict__ m1p) {
  int flat = blockIdx.x;
  flat = (flat & 7) * 128 + (flat >> 3);  // chunked XCD remap, nwg=1024
  int qt = flat & 7, h = (flat >> 3) & 15, b = (flat >> 7) & 1, part = flat >> 8;
  int bh = b * HH + h;
  int tid = threadIdx.x;
  int l = tid & 63, w = tid >> 6, c = l & 15, g = l >> 4;
  __shared__ __align__(16) unsigned short kbuf[4096];     // 8 KB
  __shared__ __align__(16) unsigned short vbuf[4096];     // 8 KB
  __shared__ __align__(16) unsigned short pws[4][2048];   // 4 x 4 KB (64q x 32t)

  const unsigned short* Kb_ =
      QKV + (long)b * SS * QS + EE + h * 64 + (long)part * 512 * QS;
  const unsigned short* Vb_ = Vt + (long)bh * 64 * SS + part * 512;
  unsigned short* Np = (part == 0) ? Np0 : (part == 1) ? Np1 : (part == 2) ? Np2 : Np3;
  const float scaleE = alpha[bh] * 0.125f;  // (1+cw)/sqrt(64)
  const f32x4 zero4 = {0.f, 0.f, 0.f, 0.f};

  // Q fragments: 4 q-subblocks x 2 k-halves, loaded once from global.
  bf16x8 qf[4][2];
  {
    const unsigned short* qp =
        QKV + ((long)b * SS + qt * 256 + w * 64 + c) * QS + h * 64;
    #pragma unroll
    for (int qb = 0; qb < 4; ++qb) {
      qf[qb][0] = *(const bf16x8*)(qp + (long)qb * 16 * QS + 8 * g);
      qf[qb][1] = *(const bf16x8*)(qp + (long)qb * 16 * QS + 32 + 8 * g);
    }
  }

  // staging addresses: 2 chunks/thread/operand, source chunk-XOR pre-swizzled
  int off1 = tid, off2 = tid + 256;
  int r1 = off1 >> 3, ch1 = ((off1 & 7) ^ (r1 & 7)) << 3;
  int r2 = off2 >> 3, ch2 = ((off2 & 7) ^ (r2 & 7)) << 3;
  const unsigned short* kg1 = Kb_ + (long)r1 * QS + ch1;
  const unsigned short* kg2 = Kb_ + (long)r2 * QS + ch2;
  const unsigned short* vg1 = Vb_ + (long)r1 * SS + ch1;
  const unsigned short* vg2 = Vb_ + (long)r2 * SS + ch2;

  // prologue: tile 0 -> regs -> LDS
  uint4 ks1 = *(const uint4*)kg1, ks2 = *(const uint4*)kg2;
  uint4 vs1 = *(const uint4*)vg1, vs2 = *(const uint4*)vg2;
  kg1 += (long)64 * QS; kg2 += (long)64 * QS; vg1 += 64; vg2 += 64;
  *(uint4*)&kbuf[off1 * 8] = ks1; *(uint4*)&kbuf[off2 * 8] = ks2;
  *(uint4*)&vbuf[off1 * 8] = vs1; *(uint4*)&vbuf[off2 * 8] = vs2;
  __syncthreads();

  f32x4 N1[4][4];  // [dblk][qb]
  #pragma unroll
  for (int d = 0; d < 4; ++d)
    #pragma unroll
    for (int qq = 0; qq < 4; ++qq) N1[d][qq] = zero4;
  float m1l0 = 0.f, m1l1 = 0.f, m1l2 = 0.f, m1l3 = 0.f;
  unsigned short* pw = pws[w];

  const int NT4 = 8;  // 512 t / 64
  for (int t = 0; t < NT4; ++t) {
    if (t + 1 < NT4) {  // issue next-tile loads early (hide HBM under compute)
      ks1 = *(const uint4*)kg1; ks2 = *(const uint4*)kg2;
      vs1 = *(const uint4*)vg1; vs2 = *(const uint4*)vg2;
      kg1 += (long)64 * QS; kg2 += (long)64 * QS; vg1 += 64; vg2 += 64;
    }
    __builtin_amdgcn_s_setprio(1);
    #pragma unroll
    for (int half = 0; half < 2; ++half) {
      #pragma unroll
      for (int mth = 0; mth < 2; ++mth) {
        int mt = half * 2 + mth;
        int r = mt * 16 + c;
        bf16x8 a0 = *(const bf16x8*)&kbuf[r * 64 + ((g ^ (r & 7)) << 3)];
        bf16x8 a1 = *(const bf16x8*)&kbuf[r * 64 + (((4 + g) ^ (r & 7)) << 3)];
        int ch = 2 * mth + (g >> 1);
        #pragma unroll
        for (int qb = 0; qb < 4; ++qb) {
          f32x4 s = mfma16(a0, qf[qb][0], zero4);
          s = mfma16(a1, qf[qb][1], s);
          float u0 = __expf(s[0] * scaleE), u1 = __expf(s[1] * scaleE);
          float u2 = __expf(s[2] * scaleE), u3 = __expf(s[3] * scaleE);
          float su = (u0 + u1) + (u2 + u3);
          if (qb == 0) m1l0 += su;
          else if (qb == 1) m1l1 += su;
          else if (qb == 2) m1l2 += su;
          else m1l3 += su;
          int row = qb * 16 + c;
          int swz = (ch ^ (row & 3) ^ ((row >> 2) & 3)) & 3;
          *(uint2*)&pw[row * 32 + (swz << 3) + ((g & 1) << 2)] =
              make_uint2(cvtpk(u0, u1), cvtpk(u2, u3));
        }
      }
      bf16x8 pf0, pf1, pf2, pf3;
      {
        int row0 = c, row1 = 16 + c, row2 = 32 + c, row3 = 48 + c;
        pf0 = *(const bf16x8*)&pw[row0 * 32 + (((g ^ (row0 & 3) ^ ((row0 >> 2) & 3)) & 3) << 3)];
        pf1 = *(const bf16x8*)&pw[row1 * 32 + (((g ^ (row1 & 3) ^ ((row1 >> 2) & 3)) & 3) << 3)];
        pf2 = *(const bf16x8*)&pw[row2 * 32 + (((g ^ (row2 & 3) ^ ((row2 >> 2) & 3)) & 3) << 3)];
        pf3 = *(const bf16x8*)&pw[row3 * 32 + (((g ^ (row3 & 3) ^ ((row3 >> 2) & 3)) & 3) << 3)];
      }
      #pragma unroll
      for (int dblk = 0; dblk < 4; ++dblk) {
        int r = dblk * 16 + c;
        bf16x8 v = *(const bf16x8*)&vbuf[r * 64 + (((half * 4 + g) ^ (r & 7)) << 3)];
        N1[dblk][0] = mfma16(v, pf0, N1[dblk][0]);
        N1[dblk][1] = mfma16(v, pf1, N1[dblk][1]);
        N1[dblk][2] = mfma16(v, pf2, N1[dblk][2]);
        N1[dblk][3] = mfma16(v, pf3, N1[dblk][3]);
      }
    }
    __builtin_amdgcn_s_setprio(0);
    __syncthreads();  // all waves done reading kbuf/vbuf
    if (t + 1 < NT4) {
      *(uint4*)&kbuf[off1 * 8] = ks1; *(uint4*)&kbuf[off2 * 8] = ks2;
      *(uint4*)&vbuf[off1 * 8] = vs1; *(uint4*)&vbuf[off2 * 8] = vs2;
    }
    __syncthreads();  // writes visible before next-tile reads
  }

  // m1 per q-col: reduce across the 4 g-lane-groups
  m1l0 += __shfl_xor(m1l0, 16); m1l0 += __shfl_xor(m1l0, 32);
  m1l1 += __shfl_xor(m1l1, 16); m1l1 += __shfl_xor(m1l1, 32);
  m1l2 += __shfl_xor(m1l2, 16); m1l2 += __shfl_xor(m1l2, 32);
  m1l3 += __shfl_xor(m1l3, 16); m1l3 += __shfl_xor(m1l3, 32);
  if (l < 16) {
    long mb = ((long)(part * BB + b) * HH + h) * SS + qt * 256 + w * 64;
    m1p[mb + c] = m1l0;
    m1p[mb + 16 + c] = m1l1;
    m1p[mb + 32 + c] = m1l2;
    m1p[mb + 48 + c] = m1l3;
  }

  #pragma unroll
  for (int qb = 0; qb < 4; ++qb) {
    unsigned short* np =
        Np + ((long)b * SS + qt * 256 + w * 64 + qb * 16 + c) * EE + h * 64;
    #pragma unroll
    for (int dblk = 0; dblk < 4; ++dblk) {
      *(uint2*)&np[dblk * 16 + 4 * g] =
          make_uint2(cvtpk(N1[dblk][qb][0], N1[dblk][qb][1]),
                     cvtpk(N1[dblk][qb][2], N1[dblk][qb][3]));
    }
  }
}

// ---------------------------------------------------------------------------
// Combine: att = bf16( (Vsum + f*(SUM Np)/(SUM m1)) / (2048+f) ).
// ---------------------------------------------------------------------------
__global__ __launch_bounds__(256) void attn_combine(
    const unsigned short* __restrict__ Np0, const unsigned short* __restrict__ Np1,
    const unsigned short* __restrict__ Np2, const unsigned short* __restrict__ Np3,
    const float* __restrict__ m1p, const float* __restrict__ Vsum,
    const float* __restrict__ factor, unsigned short* __restrict__ att) {
  int row = blockIdx.x;  // b*SS + s
  int b = row >> 11, s = row & 2047;
  int e0 = threadIdx.x * 4;
  int h = e0 >> 6, d = e0 & 63;
  int bh = b * HH + h;
  long mi = ((long)b * HH + h) * SS + s;
  const long mstep = (long)BB * HH * SS;
  float m1 = m1p[mi] + m1p[mi + mstep] + m1p[mi + 2 * mstep] + m1p[mi + 3 * mstep];
  float fac = factor[bh];
  float c1 = fac / m1;
  float invden = 1.f / ((float)SS + fac);
  long base = (long)row * EE + e0;
  ushort4 a0 = *(const ushort4*)&Np0[base];
  ushort4 a1 = *(const ushort4*)&Np1[base];
  ushort4 a2 = *(const ushort4*)&Np2[base];
  ushort4 a3 = *(const ushort4*)&Np3[base];
  float4 vs = *(const float4*)&Vsum[bh * 64 + d];
  float n0 = bf2f(a0.x) + bf2f(a1.x) + bf2f(a2.x) + bf2f(a3.x);
  float n1 = bf2f(a0.y) + bf2f(a1.y) + bf2f(a2.y) + bf2f(a3.y);
  float n2 = bf2f(a0.z) + bf2f(a1.z) + bf2f(a2.z) + bf2f(a3.z);
  float n3 = bf2f(a0.w) + bf2f(a1.w) + bf2f(a2.w) + bf2f(a3.w);
  float o0 = (vs.x + c1 * n0) * invden;
  float o1 = (vs.y + c1 * n1) * invden;
  float o2 = (vs.z + c1 * n2) * invden;
  float o3 = (vs.w + c1 * n3) * invden;
  *(uint2*)&att[base] = make_uint2(cvtpk(o0, o1), cvtpk(o2, o3));
}

// ---------------------------------------------------------------------------
// LayerNorm(x + proj) * g + b.
// ---------------------------------------------------------------------------
__global__ __launch_bounds__(256) void ln_kernel(
    const float* __restrict__ x, const float* __restrict__ proj,
    const float* __restrict__ g, const float* __restrict__ bb,
    float* __restrict__ out) {
  long row = blockIdx.x;
  const float* xp = x + row * EE;
  const float* pp = proj + row * EE;
  int tid = threadIdx.x;
  float v[4];
  float s = 0.f;
  __shared__ float r1[4], r2[4];
  #pragma unroll
  for (int i = 0; i < 4; ++i) {
    int e = tid + i * 256;
    v[i] = xp[e] + pp[e];
    s += v[i];
  }
  #pragma unroll
  for (int off = 32; off; off >>= 1) s += __shfl_xor(s, off);
  if ((tid & 63) == 0) r1[tid >> 6] = s;
  __syncthreads();
  float mean = (r1[0] + r1[1] + r1[2] + r1[3]) * (1.f / EE);
  float s2 = 0.f;
  #pragma unroll
  for (int i = 0; i < 4; ++i) { float d = v[i] - mean; s2 += d * d; }
  #pragma unroll
  for (int off = 32; off; off >>= 1) s2 += __shfl_xor(s2, off);
  if ((tid & 63) == 0) r2[tid >> 6] = s2;
  __syncthreads();
  float rstd = rsqrtf((r2[0] + r2[1] + r2[2] + r2[3]) * (1.f / EE) + 1e-5f);
  #pragma unroll
  for (int i = 0; i < 4; ++i) {
    int e = tid + i * 256;
    out[row * EE + e] = (v[i] - mean) * rstd * g[e] + bb[e];
  }
}

// ---------------------------------------------------------------------------
extern "C" void kernel_launch(void* const* d_in, const int* in_sizes, int n_in,
                              void* d_out, int out_size, void* d_ws, size_t ws_size,
                              hipStream_t stream) {
  (void)in_sizes; (void)n_in; (void)out_size; (void)ws_size;
  const float* x    = (const float*)d_in[0];
  const float* cons = (const float*)d_in[1];
  const float* Wc   = (const float*)d_in[2];
  const float* bc   = (const float*)d_in[3];
  // d_in[4] Wf, d_in[5] bf, d_in[19] phi_phase: unused (phase term cancels)
  const float* Wq   = (const float*)d_in[6];
  const float* bq   = (const float*)d_in[7];
  const float* Wk   = (const float*)d_in[8];
  const float* bk   = (const float*)d_in[9];
  const float* Wv   = (const float*)d_in[10];
  const float* bv   = (const float*)d_in[11];
  const float* Wo   = (const float*)d_in[12];
  const float* bo   = (const float*)d_in[13];
  const float* Wc1  = (const float*)d_in[14];
  const float* bc1  = (const float*)d_in[15];
  const float* Wc2  = (const float*)d_in[16];
  const float* bc2  = (const float*)d_in[17];
  const float* gate = (const float*)d_in[18];
  const float* ln_g = (const float*)d_in[20];
  const float* ln_b = (const float*)d_in[21];
  float* out = (float*)d_out;

  const size_t MSZ = (size_t)BB * SS * EE;  // 4M elems
  float* p = (float*)d_ws;
  float* beff = p;  p += BB * EE;
  float* factor = p; p += 32;
  float* alpha  = p; p += 32;
  float* Qm   = p;  p += BB * EE;   // Qm & Km adjacent: one memset
  float* Km   = p;  p += BB * EE;
  float* bqkv = p;  p += QS;
  float* Vsum = p;  p += BB * EE;
  float* proj = p;  p += MSZ;
  unsigned short* q = (unsigned short*)p;
  unsigned short* xbf  = q;  q += MSZ;
  unsigned short* cebf = q;  q += MSZ;
  unsigned short* QKVb = q;  q += 3 * MSZ;
  unsigned short* Vt   = q;  q += MSZ;
  unsigned short* attb = q;  q += MSZ;
  unsigned short* Weft = q;  q += (size_t)BB * EE * EE;
  unsigned short* Wqkvt= q;  q += (size_t)3 * EE * EE;
  unsigned short* Wot  = q;  q += (size_t)EE * EE;
  float* m1p = (float*)q;    q += 2 * 4 * BB * HH * SS;  // [4][b][h][s] f32
  // bf16 N partials alias dead regions:
  unsigned short* Np0 = xbf;                    // dead after ce gemm
  unsigned short* Np1 = cebf;                   // dead after QKV gemm
  unsigned short* Np2 = (unsigned short*)proj;  // proj written later
  unsigned short* Np3 = (unsigned short*)proj + MSZ;

  prep_pack<<<(BB * EE + QS) / 256, 256, 0, stream>>>(cons, gate, bc, bq, bk, bv,
                                                      beff, bqkv, factor);
  wceffT_kernel<<<dim3(16, 16, 2), 256, 0, stream>>>(Wc, cons, Weft);
  wT4_kernel<<<dim3(16, 16, 4), 256, 0, stream>>>(Wq, Wk, Wv, Wo, Wqkvt, Wot);
  cvt_bf_kernel<<<MSZ / 8 / 256, 256, 0, stream>>>(x, xbf);

  dim3 ggrid(EE / 64, SS / 128, BB);  // 512 wgs
  // ce = x @ Weff + beff  (bf16 out)
  gemm_bf<1><<<ggrid, 256, 0, stream>>>(xbf, Weft, beff, cebf, EE, EE,
                                        (long)SS * EE, (long)EE * EE, EE, (long)SS * EE);
  // QKV = ce @ [Wq|Wk|Wv] + [bq|bk|bv]  (bf16 out, fused N=3072, 128x128 tile)
  dim3 qgrid(QS / 128, SS / 128, BB);  // 24x16x2 = 768 wgs
  gemm128<<<qgrid, 256, 0, stream>>>(cebf, Wqkvt, bqkv, QKVb, QS, EE,
                                     (long)SS * EE, (long)SS * QS);

  hipMemsetAsync(Qm, 0, (size_t)2 * BB * EE * sizeof(float), stream);
  mean2_kernel<<<dim3((BB * EE) / 256, SS / 128, 2), 256, 0, stream>>>(QKVb, Qm, Km);
  cw_kernel<<<BB * HH, 256, 0, stream>>>(Qm, Km, Wc1, bc1, Wc2, bc2, alpha);

  repack_vT<<<dim3(SS / 64, HH, BB), 256, 0, stream>>>(QKVb + 2 * EE, Vt);
  vsum_kernel<<<(BB * EE) / 4, 256, 0, stream>>>(Vt, Vsum);

  attn_lin<<<1024, 256, 0, stream>>>(QKVb, Vt, alpha, Np0, Np1, Np2, Np3, m1p);
  attn_combine<<<BB * SS, 256, 0, stream>>>(Np0, Np1, Np2, Np3, m1p, Vsum, factor, attb);

  // proj = att @ Wo + bo  (f32 out)
  gemm_bf<0><<<ggrid, 256, 0, stream>>>(attb, Wot, bo, proj, EE, EE,
                                        (long)SS * EE, 0, 0, (long)SS * EE);
  ln_kernel<<<BB * SS, 256, 0, stream>>>(x, proj, ln_g, ln_b, out);
}

// Round 9
// 216.811 us; speedup vs baseline: 1.2326x; 1.2326x over previous
//
#include <hip/hip_runtime.h>
#include <math.h>

#define BB 2
#define SS 2048
#define EE 1024
#define HH 16
#define LL 5
#define DH 64
#define QS (3 * 1024)  // QKV fused row stride

typedef __attribute__((ext_vector_type(8))) short bf16x8;
typedef __attribute__((ext_vector_type(4))) float f32x4;

__device__ __forceinline__ unsigned short f2bf(float f) {
  unsigned u = __float_as_uint(f);
  u += 0x7fffu + ((u >> 16) & 1u);
  return (unsigned short)(u >> 16);
}
__device__ __forceinline__ float bf2f(unsigned short u) {
  return __uint_as_float((unsigned)u << 16);
}
__device__ __forceinline__ f32x4 mfma16(bf16x8 a, bf16x8 b, f32x4 c) {
  return __builtin_amdgcn_mfma_f32_16x16x32_bf16(a, b, c, 0, 0, 0);
}
// packed f32x2 -> bf16x2 (RNE), no builtin on gfx950 -> inline asm
__device__ __forceinline__ unsigned cvtpk(float a, float b) {
  unsigned r;
  asm("v_cvt_pk_bf16_f32 %0, %1, %2" : "=v"(r) : "v"(a), "v"(b));
  return r;
}
// async global->LDS, 16B per lane. lds dest must be wave-uniform base + lane*16.
__device__ __forceinline__ void gload16(const unsigned short* g, unsigned short* l) {
  __builtin_amdgcn_global_load_lds(
      (const __attribute__((address_space(1))) void*)g,
      (__attribute__((address_space(3))) void*)l, 16, 0, 0);
}

// ---------------------------------------------------------------------------
// prep_pack: factor[b][h] (thread 0); beff[b][e]; bqkv = [bq|bk|bv].
// cl computed inline from cons (cl[b][l] = cons[b*HH + l], since l%HH = l).
// ---------------------------------------------------------------------------
__global__ void prep_pack(const float* __restrict__ cons, const float* __restrict__ gate,
                          const float* __restrict__ bc,
                          const float* __restrict__ bq, const float* __restrict__ bk,
                          const float* __restrict__ bv,
                          float* __restrict__ beff, float* __restrict__ bqkv,
                          float* __restrict__ factor) {
  int i = blockIdx.x * 256 + threadIdx.x;
  if (i == 0) {
    float gw[LL][HH];
    for (int l = 0; l < LL; ++l) {
      float mx = -1e30f;
      for (int h = 0; h < HH; ++h) mx = fmaxf(mx, gate[l * HH + h]);
      float s = 0.f;
      for (int h = 0; h < HH; ++h) { gw[l][h] = expf(gate[l * HH + h] - mx); s += gw[l][h]; }
      for (int h = 0; h < HH; ++h) gw[l][h] /= s;
    }
    for (int b = 0; b < BB; ++b)
      for (int h = 0; h < HH; ++h) {
        float f = 1.f;
        for (int l = 0; l < LL; ++l) f *= 1.f + 0.1f * cons[b * HH + l] * gw[l][h];
        factor[b * HH + h] = f;
      }
  }
  if (i < BB * EE) {
    int b = i >> 10, e = i & 1023;
    float a = 0.f;
    #pragma unroll
    for (int l = 0; l < LL; ++l) a += cons[b * HH + l] * bc[l * EE + e];
    beff[i] = a * (1.f / LL);
  } else {
    int j = i - BB * EE;  // 0..3071
    float v = (j < EE) ? bq[j] : (j < 2 * EE) ? bk[j - EE] : bv[j - 2 * EE];
    bqkv[j] = v;
  }
}

// ---------------------------------------------------------------------------
// Wefft[b][o][e] (bf16) = transpose of (1/L) sum_l cl[b,l]*Wc[l][e][o].
// ---------------------------------------------------------------------------
__global__ __launch_bounds__(256) void wceffT_kernel(const float* __restrict__ Wc,
                                                     const float* __restrict__ cons,
                                                     unsigned short* __restrict__ Wt) {
  int o0 = blockIdx.x * 64, e0 = blockIdx.y * 64, b = blockIdx.z;
  __shared__ float t[64][69];
  int tid = threadIdx.x;
  float w[LL];
  #pragma unroll
  for (int l = 0; l < LL; ++l) w[l] = cons[b * HH + l] * (1.f / LL);
  #pragma unroll
  for (int i = 0; i < 4; ++i) {
    int idx = tid + i * 256;
    int r = idx >> 4, c4 = idx & 15;
    float4 acc = {0.f, 0.f, 0.f, 0.f};
    #pragma unroll
    for (int l = 0; l < LL; ++l) {
      float4 v = *(const float4*)&Wc[(long)l * EE * EE + (long)(e0 + r) * EE + o0 + c4 * 4];
      acc.x += w[l] * v.x; acc.y += w[l] * v.y; acc.z += w[l] * v.z; acc.w += w[l] * v.w;
    }
    t[r][c4 * 4 + 0] = acc.x; t[r][c4 * 4 + 1] = acc.y;
    t[r][c4 * 4 + 2] = acc.z; t[r][c4 * 4 + 3] = acc.w;
  }
  __syncthreads();
  #pragma unroll
  for (int i = 0; i < 2; ++i) {
    int idx = tid + i * 256;
    int o = idx >> 3, ech = idx & 7;
    unsigned short u[8];
    #pragma unroll
    for (int j = 0; j < 8; ++j) u[j] = f2bf(t[ech * 8 + j][o]);
    unsigned short* dst = Wt + (long)b * EE * EE + (long)(o0 + o) * EE + e0 + ech * 8;
    *(ushort4*)&dst[0] = *(ushort4*)&u[0];
    *(ushort4*)&dst[4] = *(ushort4*)&u[4];
  }
}

// ---------------------------------------------------------------------------
// wT4: transpose-convert Wq/Wk/Wv/Wo (f32 [k][n] -> bf16 [n][k]) in one launch.
// ---------------------------------------------------------------------------
__global__ __launch_bounds__(256) void wT4_kernel(
    const float* __restrict__ W0, const float* __restrict__ W1,
    const float* __restrict__ W2, const float* __restrict__ W3,
    unsigned short* __restrict__ Wqkvt, unsigned short* __restrict__ Wot) {
  int z = blockIdx.z;
  const float* W = (z == 0) ? W0 : (z == 1) ? W1 : (z == 2) ? W2 : W3;
  unsigned short* Wt = (z < 3) ? (Wqkvt + (size_t)z * EE * EE) : Wot;
  int o0 = blockIdx.x * 64, e0 = blockIdx.y * 64;
  __shared__ float t[64][69];
  int tid = threadIdx.x;
  #pragma unroll
  for (int i = 0; i < 4; ++i) {
    int idx = tid + i * 256;
    int r = idx >> 4, c4 = idx & 15;
    float4 v = *(const float4*)&W[(long)(e0 + r) * EE + o0 + c4 * 4];
    t[r][c4 * 4 + 0] = v.x; t[r][c4 * 4 + 1] = v.y;
    t[r][c4 * 4 + 2] = v.z; t[r][c4 * 4 + 3] = v.w;
  }
  __syncthreads();
  #pragma unroll
  for (int i = 0; i < 2; ++i) {
    int idx = tid + i * 256;
    int o = idx >> 3, ech = idx & 7;
    unsigned short u[8];
    #pragma unroll
    for (int j = 0; j < 8; ++j) u[j] = f2bf(t[ech * 8 + j][o]);
    unsigned short* dst = Wt + (long)(o0 + o) * EE + e0 + ech * 8;
    *(ushort4*)&dst[0] = *(ushort4*)&u[0];
    *(ushort4*)&dst[4] = *(ushort4*)&u[4];
  }
}

// f32 -> bf16 convert, 8 elems/thread.
__global__ void cvt_bf_kernel(const float* __restrict__ in, unsigned short* __restrict__ out) {
  long i = (long)blockIdx.x * 256 + threadIdx.x;
  float4 a = ((const float4*)in)[i * 2];
  float4 b = ((const float4*)in)[i * 2 + 1];
  ushort4 u0 = make_ushort4(f2bf(a.x), f2bf(a.y), f2bf(a.z), f2bf(a.w));
  ushort4 u1 = make_ushort4(f2bf(b.x), f2bf(b.y), f2bf(b.z), f2bf(b.w));
  ((ushort4*)out)[i * 2] = u0;
  ((ushort4*)out)[i * 2 + 1] = u1;
}

// ---------------------------------------------------------------------------
// bf16 MFMA GEMM, 128x128 tile (m97 structure): 4 waves, 64x64/wave, BK=64,
// double-buffered global_load_lds, chunk-XOR swizzle. All three big GEMMs.
// ---------------------------------------------------------------------------
template <int OUTBF>
__global__ __launch_bounds__(256) void gemm128(
    const unsigned short* __restrict__ A, const unsigned short* __restrict__ Bt,
    const float* __restrict__ bias, void* __restrict__ C,
    int N, int K, long As_z, long Ws_z, long Bs_z, long Cs_z) {
  int flat = blockIdx.x + gridDim.x * (blockIdx.y + gridDim.y * blockIdx.z);
  int nwg = gridDim.x * gridDim.y * gridDim.z;
  flat = (flat & 7) * (nwg >> 3) + (flat >> 3);
  int nt_ = flat % gridDim.x;
  int rest = flat / gridDim.x;
  int mt_ = rest % gridDim.y;
  int z = rest / gridDim.y;

  const unsigned short* Ab = A + z * As_z + (long)mt_ * 128 * K;
  const unsigned short* Bb = Bt + z * Ws_z + (long)nt_ * 128 * K;
  const float* bb = bias + z * Bs_z + nt_ * 128;

  __shared__ __align__(16) unsigned short As[2][128 * 64];
  __shared__ __align__(16) unsigned short Bs[2][128 * 64];
  int tid = threadIdx.x;
  int w = tid >> 6, lane = tid & 63, c = lane & 15, g = lane >> 4;
  int wrow = (w >> 1) * 64, wcol = (w & 1) * 64;

  #define STG128(srcp, dstbuf, kt)                                             \
    {                                                                          \
      const unsigned short* s_ = (srcp) + (kt) * 64;                           \
      _Pragma("unroll") for (int j = 0; j < 4; ++j) {                          \
        int idx = tid + j * 256;                                               \
        int row = idx >> 3, ch = idx & 7;                                      \
        gload16(s_ + (long)row * K + ((ch ^ (row & 7)) << 3),                  \
                &dstbuf[(idx & ~63) * 8 + (lane)*8]);                          \
      }                                                                        \
    }

  f32x4 acc[4][4];
  #pragma unroll
  for (int mi = 0; mi < 4; ++mi)
    #pragma unroll
    for (int ni = 0; ni < 4; ++ni) acc[mi][ni] = {0.f, 0.f, 0.f, 0.f};

  int nk = K >> 6;
  STG128(Ab, As[0], 0) STG128(Bb, Bs[0], 0)
  __syncthreads();
  int buf = 0;
  for (int kt = 0; kt < nk; ++kt) {
    if (kt + 1 < nk) { STG128(Ab, As[buf ^ 1], kt + 1) STG128(Bb, Bs[buf ^ 1], kt + 1) }
    #pragma unroll
    for (int kk = 0; kk < 2; ++kk) {
      bf16x8 af[4], bfv[4];
      #pragma unroll
      for (int mi = 0; mi < 4; ++mi) {
        int row = wrow + mi * 16 + c;
        af[mi] = *(const bf16x8*)&As[buf][row * 64 + ((((kk << 2) + g) ^ (row & 7)) << 3)];
      }
      #pragma unroll
      for (int ni = 0; ni < 4; ++ni) {
        int row = wcol + ni * 16 + c;
        bfv[ni] = *(const bf16x8*)&Bs[buf][row * 64 + ((((kk << 2) + g) ^ (row & 7)) << 3)];
      }
      #pragma unroll
      for (int mi = 0; mi < 4; ++mi)
        #pragma unroll
        for (int ni = 0; ni < 4; ++ni)
          acc[mi][ni] = mfma16(af[mi], bfv[ni], acc[mi][ni]);
    }
    __syncthreads();
    buf ^= 1;
  }

  float bval[4];
  #pragma unroll
  for (int ni = 0; ni < 4; ++ni) bval[ni] = bb[wcol + ni * 16 + c];
  #pragma unroll
  for (int mi = 0; mi < 4; ++mi)
    #pragma unroll
    for (int ni = 0; ni < 4; ++ni) {
      long col = (long)nt_ * 128 + wcol + ni * 16 + c;
      #pragma unroll
      for (int r = 0; r < 4; ++r) {
        long row = (long)mt_ * 128 + wrow + mi * 16 + g * 4 + r;
        float v = acc[mi][ni][r] + bval[ni];
        if (OUTBF)
          ((unsigned short*)C)[z * Cs_z + row * N + col] = f2bf(v);
        else
          ((float*)C)[z * Cs_z + row * N + col] = v;
      }
    }
  #undef STG128
}

// ---------------------------------------------------------------------------
// mean2: partial mean over s of Q (z=0) and K (z=1) slices of QKV.
// ---------------------------------------------------------------------------
__global__ void mean2_kernel(const unsigned short* __restrict__ QKVb,
                             float* __restrict__ Qm, float* __restrict__ Km) {
  int z = blockIdx.z;
  const unsigned short* in = QKVb + z * EE;
  float* out = z ? Km : Qm;
  int e = blockIdx.x * 256 + threadIdx.x;
  int b = e >> 10, ee = e & 1023;
  int s0 = blockIdx.y * 128;
  const unsigned short* p = in + ((long)b * SS + s0) * QS + ee;
  float acc = 0.f;
  for (int i = 0; i < 128; ++i) acc += bf2f(p[(long)i * QS]);
  atomicAdd(&out[e], acc * (1.f / SS));
}

// ---------------------------------------------------------------------------
// alpha[b,h] = 1 + sigmoid( gelu(ci @ Wc1 + bc1) @ Wc2 + bc2 ).
// ---------------------------------------------------------------------------
__global__ __launch_bounds__(256) void cw_kernel(
    const float* __restrict__ Qm, const float* __restrict__ Km,
    const float* __restrict__ Wc1, const float* __restrict__ bc1,
    const float* __restrict__ Wc2, const float* __restrict__ bc2,
    float* __restrict__ alpha) {
  int bh = blockIdx.x, b = bh / HH, h = bh % HH;
  __shared__ float ci[128];
  __shared__ float pr[4];
  int tid = threadIdx.x;
  if (tid < 64) ci[tid] = Qm[b * EE + h * DH + tid];
  else if (tid < 128) ci[tid] = Km[b * EE + h * DH + (tid - 64)];
  __syncthreads();
  float part = 0.f;
  for (int j = tid; j < EE; j += 256) {
    float acc = bc1[j];
    #pragma unroll 8
    for (int i = 0; i < 128; ++i) acc += ci[i] * Wc1[i * EE + j];
    float ge = 0.5f * acc * (1.f + erff(acc * 0.70710678118654752f));
    part += ge * Wc2[j];
  }
  #pragma unroll
  for (int off = 32; off; off >>= 1) part += __shfl_xor(part, off);
  if ((tid & 63) == 0) pr[tid >> 6] = part;
  __syncthreads();
  if (tid == 0) {
    float tot = pr[0] + pr[1] + pr[2] + pr[3] + bc2[0];
    float cw = 1.f / (1.f + expf(-tot));
    alpha[bh] = 1.f + cw;
  }
}

// ---------------------------------------------------------------------------
// Repack V bf16 (QKV fused, stride QS) -> bf16 transposed Vt[bh][d][s].
// ---------------------------------------------------------------------------
__global__ __launch_bounds__(256) void repack_vT(const unsigned short* __restrict__ Vh,
                                                 unsigned short* __restrict__ Vt) {
  int st = blockIdx.x, h = blockIdx.y, b = blockIdx.z;
  __shared__ unsigned short tile[64][66];
  int tid = threadIdx.x;
  const unsigned short* src = Vh + ((long)(b * SS) + st * 64) * QS + h * 64;
  #pragma unroll
  for (int i = 0; i < 2; ++i) {
    int idx = tid + i * 256;
    int s = idx >> 3, ch = idx & 7;
    #pragma unroll
    for (int j = 0; j < 8; ++j) tile[s][ch * 8 + j] = src[(long)s * QS + ch * 8 + j];
  }
  __syncthreads();
  unsigned short* dst = Vt + ((long)(b * HH + h) * 64) * SS + st * 64;
  #pragma unroll
  for (int i = 0; i < 2; ++i) {
    int idx = tid + i * 256;
    int d = idx >> 3, sch = idx & 7;
    unsigned short u[8];
    #pragma unroll
    for (int j = 0; j < 8; ++j) u[j] = tile[sch * 8 + j][d];
    *(ushort4*)&dst[(long)d * SS + sch * 8] = *(ushort4*)&u[0];
    *(ushort4*)&dst[(long)d * SS + sch * 8 + 4] = *(ushort4*)&u[4];
  }
}

// ---------------------------------------------------------------------------
// Vsum[bh*64+d] = sum_s Vt[bh][d][s].  One wave per row.
// ---------------------------------------------------------------------------
__global__ __launch_bounds__(256) void vsum_kernel(const unsigned short* __restrict__ Vt,
                                                   float* __restrict__ Vsum) {
  int row = blockIdx.x * 4 + (threadIdx.x >> 6);
  int lane = threadIdx.x & 63;
  const unsigned short* p = Vt + (long)row * SS + lane * 32;
  float acc = 0.f;
  #pragma unroll
  for (int i = 0; i < 4; ++i) {
    uint4 v = *(const uint4*)(p + i * 8);
    unsigned arr[4] = {v.x, v.y, v.z, v.w};
    #pragma unroll
    for (int j = 0; j < 4; ++j) {
      acc += __uint_as_float(arr[j] << 16);
      acc += __uint_as_float(arr[j] & 0xffff0000u);
    }
  }
  #pragma unroll
  for (int off = 32; off; off >>= 1) acc += __shfl_xor(acc, off);
  if (lane == 0) Vsum[row] = acc;
}

// ---------------------------------------------------------------------------
// Linearized attention (round-7 proven config): t-split x2, 24KB LDS,
// 4 waves x 32 q = 128 q/block, single-buffered K/V with T14 reg-staging,
// P through 2KB wave-private LDS in two 32-t halves.
// Partials: m1p[part][b][h][s] f32; Np[part][b][s][e] f32.
// ---------------------------------------------------------------------------
__global__ __launch_bounds__(256, 4) void attn_lin(
    const unsigned short* __restrict__ QKV,  // [b][s][3072]
    const unsigned short* __restrict__ Vt,   // [bh][d][s]
    const float* __restrict__ alpha,
    float* __restrict__ Np0, float* __restrict__ Np1,
    float* __restrict__ m1p) {
  int flat = blockIdx.x;
  flat = (flat & 7) * 128 + (flat >> 3);  // chunked XCD remap, nwg=1024
  int qt = flat & 15, h = (flat >> 4) & 15, b = (flat >> 8) & 1, part = flat >> 9;
  int bh = b * HH + h;
  int tid = threadIdx.x;
  int l = tid & 63, w = tid >> 6, c = l & 15, g = l >> 4;
  __shared__ __align__(16) unsigned short kbuf[4096];      // 8 KB
  __shared__ __align__(16) unsigned short vbuf[4096];      // 8 KB
  __shared__ __align__(16) unsigned short pws[4][1024];    // 4 x 2 KB

  const unsigned short* Kb_ =
      QKV + (long)b * SS * QS + EE + h * 64 + (long)part * 1024 * QS;
  const unsigned short* Vb_ = Vt + (long)bh * 64 * SS + part * 1024;
  float* Np = part ? Np1 : Np0;
  const float scaleE = alpha[bh] * 0.125f;  // (1+cw)/sqrt(64)
  const f32x4 zero4 = {0.f, 0.f, 0.f, 0.f};

  // Q fragments: 2 q-subblocks x 2 k-halves, loaded once from global.
  bf16x8 qf[2][2];
  {
    const unsigned short* qp =
        QKV + ((long)b * SS + qt * 128 + w * 32 + c) * QS + h * 64;
    qf[0][0] = *(const bf16x8*)(qp + 8 * g);
    qf[0][1] = *(const bf16x8*)(qp + 32 + 8 * g);
    qf[1][0] = *(const bf16x8*)(qp + 16 * QS + 8 * g);
    qf[1][1] = *(const bf16x8*)(qp + 16 * QS + 32 + 8 * g);
  }

  // staging addresses: 2 chunks/thread/operand, source chunk-XOR pre-swizzled
  int off1 = tid, off2 = tid + 256;
  int r1 = off1 >> 3, ch1 = ((off1 & 7) ^ (r1 & 7)) << 3;
  int r2 = off2 >> 3, ch2 = ((off2 & 7) ^ (r2 & 7)) << 3;
  const unsigned short* kg1 = Kb_ + (long)r1 * QS + ch1;
  const unsigned short* kg2 = Kb_ + (long)r2 * QS + ch2;
  const unsigned short* vg1 = Vb_ + (long)r1 * SS + ch1;
  const unsigned short* vg2 = Vb_ + (long)r2 * SS + ch2;

  // prologue: tile 0 -> regs -> LDS
  uint4 ks1 = *(const uint4*)kg1, ks2 = *(const uint4*)kg2;
  uint4 vs1 = *(const uint4*)vg1, vs2 = *(const uint4*)vg2;
  kg1 += (long)64 * QS; kg2 += (long)64 * QS; vg1 += 64; vg2 += 64;
  *(uint4*)&kbuf[off1 * 8] = ks1; *(uint4*)&kbuf[off2 * 8] = ks2;
  *(uint4*)&vbuf[off1 * 8] = vs1; *(uint4*)&vbuf[off2 * 8] = vs2;
  __syncthreads();

  f32x4 N1[4][2];
  #pragma unroll
  for (int d = 0; d < 4; ++d) { N1[d][0] = zero4; N1[d][1] = zero4; }
  float m1l0 = 0.f, m1l1 = 0.f;
  unsigned short* pw = pws[w];

  const int NT2 = 16;  // 1024 t / 64
  for (int t = 0; t < NT2; ++t) {
    if (t + 1 < NT2) {  // issue next-tile loads early (hide HBM under compute)
      ks1 = *(const uint4*)kg1; ks2 = *(const uint4*)kg2;
      vs1 = *(const uint4*)vg1; vs2 = *(const uint4*)vg2;
      kg1 += (long)64 * QS; kg2 += (long)64 * QS; vg1 += 64; vg2 += 64;
    }
    __builtin_amdgcn_s_setprio(1);
    #pragma unroll
    for (int half = 0; half < 2; ++half) {
      // QK^T for this 32-t half; u = exp(scale*s); pack into 2KB P-half
      #pragma unroll
      for (int mth = 0; mth < 2; ++mth) {
        int mt = half * 2 + mth;
        int r = mt * 16 + c;
        bf16x8 a0 = *(const bf16x8*)&kbuf[r * 64 + ((g ^ (r & 7)) << 3)];
        bf16x8 a1 = *(const bf16x8*)&kbuf[r * 64 + (((4 + g) ^ (r & 7)) << 3)];
        int ch = 2 * mth + (g >> 1);
        #pragma unroll
        for (int qb = 0; qb < 2; ++qb) {
          f32x4 s = mfma16(a0, qf[qb][0], zero4);
          s = mfma16(a1, qf[qb][1], s);
          float u0 = __expf(s[0] * scaleE), u1 = __expf(s[1] * scaleE);
          float u2 = __expf(s[2] * scaleE), u3 = __expf(s[3] * scaleE);
          if (qb == 0) m1l0 += (u0 + u1) + (u2 + u3);
          else         m1l1 += (u0 + u1) + (u2 + u3);
          int row = qb * 16 + c;
          int swz = (ch ^ (row & 3) ^ ((row >> 2) & 3)) & 3;
          *(uint2*)&pw[row * 32 + (swz << 3) + ((g & 1) << 2)] =
              make_uint2(cvtpk(u0, u1), cvtpk(u2, u3));
        }
      }
      // P fragments (wave-private; compiler orders via lgkmcnt)
      bf16x8 pf[2];
      #pragma unroll
      for (int qb = 0; qb < 2; ++qb) {
        int row = qb * 16 + c;
        int swz = (g ^ (row & 3) ^ ((row >> 2) & 3)) & 3;
        pf[qb] = *(const bf16x8*)&pw[row * 32 + (swz << 3)];
      }
      // PV for this t-half: N1[d][q] += V[d][t-half] * P[t-half][q]
      #pragma unroll
      for (int dblk = 0; dblk < 4; ++dblk) {
        int r = dblk * 16 + c;
        bf16x8 v = *(const bf16x8*)&vbuf[r * 64 + (((half * 4 + g) ^ (r & 7)) << 3)];
        N1[dblk][0] = mfma16(v, pf[0], N1[dblk][0]);
        N1[dblk][1] = mfma16(v, pf[1], N1[dblk][1]);
      }
    }
    __builtin_amdgcn_s_setprio(0);
    __syncthreads();  // all waves done reading kbuf/vbuf
    if (t + 1 < NT2) {  // write next tile (compiler inserts vmcnt wait)
      *(uint4*)&kbuf[off1 * 8] = ks1; *(uint4*)&kbuf[off2 * 8] = ks2;
      *(uint4*)&vbuf[off1 * 8] = vs1; *(uint4*)&vbuf[off2 * 8] = vs2;
    }
    __syncthreads();  // writes visible before next-tile reads
  }

  // m1 per q-col: reduce across the 4 g-lane-groups
  m1l0 += __shfl_xor(m1l0, 16); m1l0 += __shfl_xor(m1l0, 32);
  m1l1 += __shfl_xor(m1l1, 16); m1l1 += __shfl_xor(m1l1, 32);
  if (l < 16) {
    long mb = ((long)(part * BB + b) * HH + h) * SS + qt * 128 + w * 32;
    m1p[mb + c] = m1l0;
    m1p[mb + 16 + c] = m1l1;
  }

  #pragma unroll
  for (int qb = 0; qb < 2; ++qb) {
    float* np = Np + ((long)b * SS + qt * 128 + w * 32 + qb * 16 + c) * EE + h * 64;
    #pragma unroll
    for (int dblk = 0; dblk < 4; ++dblk) {
      float4 o = {N1[dblk][qb][0], N1[dblk][qb][1], N1[dblk][qb][2], N1[dblk][qb][3]};
      *(float4*)&np[dblk * 16 + 4 * g] = o;
    }
  }
}

// ---------------------------------------------------------------------------
// Combine: att = bf16( (Vsum + f*(N0+N1)/(m1a+m1b)) / (2048+f) ).
// ---------------------------------------------------------------------------
__global__ __launch_bounds__(256) void attn_combine(
    const float* __restrict__ Np0, const float* __restrict__ Np1,
    const float* __restrict__ m1p, const float* __restrict__ Vsum,
    const float* __restrict__ factor, unsigned short* __restrict__ att) {
  int row = blockIdx.x;  // b*SS + s
  int b = row >> 11, s = row & 2047;
  int e0 = threadIdx.x * 4;
  int h = e0 >> 6, d = e0 & 63;
  int bh = b * HH + h;
  float m1 = m1p[((long)b * HH + h) * SS + s] +
             m1p[((long)(BB + b) * HH + h) * SS + s];
  float fac = factor[bh];
  float c1 = fac / m1;
  float invden = 1.f / ((float)SS + fac);
  long base = (long)row * EE + e0;
  float4 n0 = *(const float4*)&Np0[base];
  float4 n1 = *(const float4*)&Np1[base];
  float4 vs = *(const float4*)&Vsum[bh * 64 + d];
  float o0 = (vs.x + c1 * (n0.x + n1.x)) * invden;
  float o1 = (vs.y + c1 * (n0.y + n1.y)) * invden;
  float o2 = (vs.z + c1 * (n0.z + n1.z)) * invden;
  float o3 = (vs.w + c1 * (n0.w + n1.w)) * invden;
  *(uint2*)&att[base] = make_uint2(cvtpk(o0, o1), cvtpk(o2, o3));
}

// ---------------------------------------------------------------------------
// LayerNorm(x + proj) * g + b.
// ---------------------------------------------------------------------------
__global__ __launch_bounds__(256) void ln_kernel(
    const float* __restrict__ x, const float* __restrict__ proj,
    const float* __restrict__ g, const float* __restrict__ bb,
    float* __restrict__ out) {
  long row = blockIdx.x;
  const float* xp = x + row * EE;
  const float* pp = proj + row * EE;
  int tid = threadIdx.x;
  float v[4];
  float s = 0.f;
  __shared__ float r1[4], r2[4];
  #pragma unroll
  for (int i = 0; i < 4; ++i) {
    int e = tid + i * 256;
    v[i] = xp[e] + pp[e];
    s += v[i];
  }
  #pragma unroll
  for (int off = 32; off; off >>= 1) s += __shfl_xor(s, off);
  if ((tid & 63) == 0) r1[tid >> 6] = s;
  __syncthreads();
  float mean = (r1[0] + r1[1] + r1[2] + r1[3]) * (1.f / EE);
  float s2 = 0.f;
  #pragma unroll
  for (int i = 0; i < 4; ++i) { float d = v[i] - mean; s2 += d * d; }
  #pragma unroll
  for (int off = 32; off; off >>= 1) s2 += __shfl_xor(s2, off);
  if ((tid & 63) == 0) r2[tid >> 6] = s2;
  __syncthreads();
  float rstd = rsqrtf((r2[0] + r2[1] + r2[2] + r2[3]) * (1.f / EE) + 1e-5f);
  #pragma unroll
  for (int i = 0; i < 4; ++i) {
    int e = tid + i * 256;
    out[row * EE + e] = (v[i] - mean) * rstd * g[e] + bb[e];
  }
}

// ---------------------------------------------------------------------------
extern "C" void kernel_launch(void* const* d_in, const int* in_sizes, int n_in,
                              void* d_out, int out_size, void* d_ws, size_t ws_size,
                              hipStream_t stream) {
  (void)in_sizes; (void)n_in; (void)out_size; (void)ws_size;
  const float* x    = (const float*)d_in[0];
  const float* cons = (const float*)d_in[1];
  const float* Wc   = (const float*)d_in[2];
  const float* bc   = (const float*)d_in[3];
  // d_in[4] Wf, d_in[5] bf, d_in[19] phi_phase: unused (phase term cancels)
  const float* Wq   = (const float*)d_in[6];
  const float* bq   = (const float*)d_in[7];
  const float* Wk   = (const float*)d_in[8];
  const float* bk   = (const float*)d_in[9];
  const float* Wv   = (const float*)d_in[10];
  const float* bv   = (const float*)d_in[11];
  const float* Wo   = (const float*)d_in[12];
  const float* bo   = (const float*)d_in[13];
  const float* Wc1  = (const float*)d_in[14];
  const float* bc1  = (const float*)d_in[15];
  const float* Wc2  = (const float*)d_in[16];
  const float* bc2  = (const float*)d_in[17];
  const float* gate = (const float*)d_in[18];
  const float* ln_g = (const float*)d_in[20];
  const float* ln_b = (const float*)d_in[21];
  float* out = (float*)d_out;

  const size_t MSZ = (size_t)BB * SS * EE;  // 4M elems
  float* p = (float*)d_ws;
  float* beff = p;  p += BB * EE;
  float* factor = p; p += 32;
  float* alpha  = p; p += 32;
  float* Qm   = p;  p += BB * EE;   // Qm & Km adjacent: one memset
  float* Km   = p;  p += BB * EE;
  float* bqkv = p;  p += QS;
  float* Vsum = p;  p += BB * EE;
  float* proj = p;  p += MSZ;
  unsigned short* q = (unsigned short*)p;
  unsigned short* xbf  = q;  q += MSZ;
  unsigned short* cebf = q;  q += MSZ;
  unsigned short* QKVb = q;  q += 3 * MSZ;
  unsigned short* Vt   = q;  q += MSZ;
  unsigned short* attb = q;  q += MSZ;
  unsigned short* Weft = q;  q += (size_t)BB * EE * EE;
  unsigned short* Wqkvt= q;  q += (size_t)3 * EE * EE;
  unsigned short* Wot  = q;  q += (size_t)EE * EE;
  float* m1p = (float*)q;    q += 2 * 2 * BB * HH * SS;  // [2][b][h][s] f32
  // f32 N partials alias dead regions:
  float* Np0 = (float*)xbf;  // xbf+cebf dead after the two gemms
  float* Np1 = proj;         // proj written later by out-proj gemm

  prep_pack<<<(BB * EE + QS) / 256, 256, 0, stream>>>(cons, gate, bc, bq, bk, bv,
                                                      beff, bqkv, factor);
  wceffT_kernel<<<dim3(16, 16, 2), 256, 0, stream>>>(Wc, cons, Weft);
  wT4_kernel<<<dim3(16, 16, 4), 256, 0, stream>>>(Wq, Wk, Wv, Wo, Wqkvt, Wot);
  cvt_bf_kernel<<<MSZ / 8 / 256, 256, 0, stream>>>(x, xbf);

  // ce = x @ Weff + beff  (bf16 out, 128x128 tile)
  dim3 cgrid(EE / 128, SS / 128, BB);  // 8x16x2 = 256 wgs
  gemm128<1><<<cgrid, 256, 0, stream>>>(xbf, Weft, beff, cebf, EE, EE,
                                        (long)SS * EE, (long)EE * EE, EE, (long)SS * EE);
  // QKV = ce @ [Wq|Wk|Wv] + [bq|bk|bv]  (bf16 out, fused N=3072)
  dim3 qgrid(QS / 128, SS / 128, BB);  // 24x16x2 = 768 wgs
  gemm128<1><<<qgrid, 256, 0, stream>>>(cebf, Wqkvt, bqkv, QKVb, QS, EE,
                                        (long)SS * EE, 0, 0, (long)SS * QS);

  hipMemsetAsync(Qm, 0, (size_t)2 * BB * EE * sizeof(float), stream);
  mean2_kernel<<<dim3((BB * EE) / 256, SS / 128, 2), 256, 0, stream>>>(QKVb, Qm, Km);
  cw_kernel<<<BB * HH, 256, 0, stream>>>(Qm, Km, Wc1, bc1, Wc2, bc2, alpha);

  repack_vT<<<dim3(SS / 64, HH, BB), 256, 0, stream>>>(QKVb + 2 * EE, Vt);
  vsum_kernel<<<(BB * EE) / 4, 256, 0, stream>>>(Vt, Vsum);

  attn_lin<<<1024, 256, 0, stream>>>(QKVb, Vt, alpha, Np0, Np1, m1p);
  attn_combine<<<BB * SS, 256, 0, stream>>>(Np0, Np1, m1p, Vsum, factor, attb);

  // proj = att @ Wo + bo  (f32 out, 128x128 tile)
  gemm128<0><<<cgrid, 256, 0, stream>>>(attb, Wot, bo, proj, EE, EE,
                                        (long)SS * EE, 0, 0, (long)SS * EE);
  ln_kernel<<<BB * SS, 256, 0, stream>>>(x, proj, ln_g, ln_b, out);
}